// Round 10
// baseline (120.978 us; speedup 1.0000x reference)
//
#include <hip/hip_runtime.h>

#define HIDDEN 4096
#define RANK   256
#define G      16     // HIDDEN / RANK
#define TW     8      // tokens per wave in expand

typedef _Float16 h2d __attribute__((ext_vector_type(2)));
typedef float    f4v __attribute__((ext_vector_type(4)));

__device__ __forceinline__ unsigned int pkf16(float a, float b) {
    auto h = __builtin_amdgcn_cvt_pkrtz(a, b);
    return __builtin_bit_cast(unsigned int, h);
}
__device__ __forceinline__ float dot2(unsigned int a, unsigned int b, float c) {
    return __builtin_amdgcn_fdot2(__builtin_bit_cast(h2d, a),
                                  __builtin_bit_cast(h2d, b), c, false);
}

// ---------------------------------------------------------------------------
// pack: Mp[pr*256 + k] = {f16 M[2pr][k], f16 M[2pr+1][k]}   (128 KB, once)
// ---------------------------------------------------------------------------
__global__ __launch_bounds__(256)
void mora_pack(const float* __restrict__ Mg, unsigned int* __restrict__ Mp) {
    const int idx = blockIdx.x * 256 + threadIdx.x;    // 0..32767
    const int pr  = idx >> 8;
    const int k   = idx & 255;
    Mp[idx] = pkf16(Mg[(size_t)(2 * pr) * RANK + k],
                    Mg[(size_t)(2 * pr + 1) * RANK + k]);
}

// ---------------------------------------------------------------------------
// k1: read-stream phase. Thread = one float4 of comp; writes comp PACKED as
//     f16 pairs (uint2) -> comp is 8 MB and expand needs no repack.
// ---------------------------------------------------------------------------
__global__ __launch_bounds__(256)
void mora_compress(const float* __restrict__ x,      // [T, HIDDEN]
                   uint2* __restrict__ comp_pk)      // [T][128] f16 pair-pack
{
    const long i  = (long)blockIdx.x * 256 + threadIdx.x;  // 0..1048575
    const long t  = i >> 6;
    const int  r4 = (int)(i & 63);

    const float4* xr = (const float4*)(x + t * HIDDEN) + r4;
    float4 e = xr[0];
    float4 o = xr[64];
    #pragma unroll
    for (int gi = 1; gi < G / 2; ++gi) {      // two independent chains (ILP)
        const float4 a = xr[(2 * gi) * 64];
        const float4 b = xr[(2 * gi + 1) * 64];
        e.x += a.x; e.y += a.y; e.z += a.z; e.w += a.w;
        o.x += b.x; o.y += b.y; o.z += b.z; o.w += b.w;
    }
    e.x += o.x; e.y += o.y; e.z += o.z; e.w += o.w;
    comp_pk[t * (RANK / 2) + 2 * r4] = make_uint2(pkf16(e.x, e.y),
                                                  pkf16(e.z, e.w));
}

// ---------------------------------------------------------------------------
// k2: write-stream phase. Wave owns TW=8 tokens: M read once per 8 tokens
//     (256 MB total L2 traffic, 4x less than R9), dot2 accumulate,
//     NONTEMPORAL coalesced splat stores.
// ---------------------------------------------------------------------------
__global__ __launch_bounds__(256)
void mora_expand(const uint2* __restrict__ comp_pk,     // [T][128]
                 const unsigned int* __restrict__ Mp,   // [128][256] f16 pairs
                 float* __restrict__ out)               // [T, HIDDEN]
{
    __shared__ float ost[4][RANK];          // per-wave private, no barriers

    const int  tid  = threadIdx.x;
    const int  w    = tid >> 6;
    const int  l    = tid & 63;
    const long tok0 = (long)blockIdx.x * (4 * TW) + (long)w * TW;

    // comp (already f16-packed): lane l owns rows 4l..4l+3 = pairs 2l, 2l+1
    unsigned int cp0[TW], cp1[TW];
    #pragma unroll
    for (int t = 0; t < TW; ++t) {
        const uint2 c = comp_pk[(tok0 + t) * (RANK / 2) + 2 * l];
        cp0[t] = c.x;
        cp1[t] = c.y;
    }

    float acc[TW][4];
    #pragma unroll
    for (int t = 0; t < TW; ++t) {
        acc[t][0] = 0.f; acc[t][1] = 0.f; acc[t][2] = 0.f; acc[t][3] = 0.f;
    }

    const uint4* Mp4 = (const uint4*)Mp;    // pair-row stride = 64 uint4
    #pragma unroll 2
    for (int i = 0; i < 32; ++i) {
        const uint4 m0 = Mp4[(4 * i + 0) * 64 + l];   // coalesced 1 KiB, L2-hot
        const uint4 m1 = Mp4[(4 * i + 1) * 64 + l];
        const uint4 m2 = Mp4[(4 * i + 2) * 64 + l];
        const uint4 m3 = Mp4[(4 * i + 3) * 64 + l];
        #pragma unroll
        for (int t = 0; t < TW; ++t) {
            const unsigned sA = (unsigned)__builtin_amdgcn_readlane((int)cp0[t], 2 * i);
            const unsigned sB = (unsigned)__builtin_amdgcn_readlane((int)cp1[t], 2 * i);
            const unsigned sC = (unsigned)__builtin_amdgcn_readlane((int)cp0[t], 2 * i + 1);
            const unsigned sD = (unsigned)__builtin_amdgcn_readlane((int)cp1[t], 2 * i + 1);
            acc[t][0] = dot2(sA, m0.x, acc[t][0]);
            acc[t][1] = dot2(sA, m0.y, acc[t][1]);
            acc[t][2] = dot2(sA, m0.z, acc[t][2]);
            acc[t][3] = dot2(sA, m0.w, acc[t][3]);
            acc[t][0] = dot2(sB, m1.x, acc[t][0]);
            acc[t][1] = dot2(sB, m1.y, acc[t][1]);
            acc[t][2] = dot2(sB, m1.z, acc[t][2]);
            acc[t][3] = dot2(sB, m1.w, acc[t][3]);
            acc[t][0] = dot2(sC, m2.x, acc[t][0]);
            acc[t][1] = dot2(sC, m2.y, acc[t][1]);
            acc[t][2] = dot2(sC, m2.z, acc[t][2]);
            acc[t][3] = dot2(sC, m2.w, acc[t][3]);
            acc[t][0] = dot2(sD, m3.x, acc[t][0]);
            acc[t][1] = dot2(sD, m3.y, acc[t][1]);
            acc[t][2] = dot2(sD, m3.z, acc[t][2]);
            acc[t][3] = dot2(sD, m3.w, acc[t][3]);
        }
    }

    // restage per wave, then NONTEMPORAL coalesced splat stores
    #pragma unroll
    for (int t = 0; t < TW; ++t) {
        ((float4*)ost[w])[l] =
            make_float4(acc[t][0], acc[t][1], acc[t][2], acc[t][3]);
        f4v* orow = (f4v*)(out + (tok0 + t) * HIDDEN);
        #pragma unroll
        for (int s = 0; s < 16; ++s) {
            const float v = ost[w][(s << 4) + (l >> 2)];  // 4-lane bcast, no conflict
            const f4v sp = {v, v, v, v};
            __builtin_nontemporal_store(sp, orow + (s << 6) + l);
        }
    }
}

extern "C" void kernel_launch(void* const* d_in, const int* in_sizes, int n_in,
                              void* d_out, int out_size, void* d_ws, size_t ws_size,
                              hipStream_t stream) {
    const float* x = (const float*)d_in[0];
    const float* M = (const float*)d_in[1];
    float* out     = (float*)d_out;

    unsigned int* Mp      = (unsigned int*)d_ws;               // 128 KiB
    uint2*        comp_pk = (uint2*)((char*)d_ws + 131072);    // 16 MiB

    const int T = in_sizes[0] / HIDDEN;     // 16384 tokens

    hipLaunchKernelGGL(mora_pack, dim3(128), dim3(256), 0, stream, M, Mp);
    hipLaunchKernelGGL(mora_compress, dim3(T * (RANK / 4) / 256), dim3(256),
                       0, stream, x, comp_pk);
    hipLaunchKernelGGL(mora_expand, dim3(T / (4 * TW)), dim3(256), 0, stream,
                       comp_pk, Mp, out);
}

// Round 11
// 106.695 us; speedup vs baseline: 1.1339x; 1.1339x over previous
//
#include <hip/hip_runtime.h>

#define HIDDEN 4096
#define RANK   256
#define G      16     // HIDDEN / RANK
#define TWX    4      // tokens per wave in expand (wave covers 4 tok x 128 cols)

typedef _Float16 h2d __attribute__((ext_vector_type(2)));
typedef float    f4v __attribute__((ext_vector_type(4)));

__device__ __forceinline__ unsigned int pkf16(float a, float b) {
    auto h = __builtin_amdgcn_cvt_pkrtz(a, b);
    return __builtin_bit_cast(unsigned int, h);
}
__device__ __forceinline__ float dot2(unsigned int a, unsigned int b, float c) {
    return __builtin_amdgcn_fdot2(__builtin_bit_cast(h2d, a),
                                  __builtin_bit_cast(h2d, b), c, false);
}

// ---------------------------------------------------------------------------
// pack: Mp[pr*256 + k] = {f16 M[2pr][k], f16 M[2pr+1][k]}   (128 KB, once)
// ---------------------------------------------------------------------------
__global__ __launch_bounds__(256)
void mora_pack(const float* __restrict__ Mg, unsigned int* __restrict__ Mp) {
    const int idx = blockIdx.x * 256 + threadIdx.x;    // 0..32767
    const int pr  = idx >> 8;
    const int k   = idx & 255;
    Mp[idx] = pkf16(Mg[(size_t)(2 * pr) * RANK + k],
                    Mg[(size_t)(2 * pr + 1) * RANK + k]);
}

// ---------------------------------------------------------------------------
// k1: read-stream phase. Thread = one float4 of comp; writes comp DENSE as
//     f16 pair-pack: comp_pk[t*64 + r4] = {pk(r0,r1), pk(r2,r3)} of rows
//     4*r4..4*r4+3. Fully coalesced 512 B/wave on write and later read.
// ---------------------------------------------------------------------------
__global__ __launch_bounds__(256)
void mora_compress(const float* __restrict__ x,      // [T, HIDDEN]
                   uint2* __restrict__ comp_pk)      // [T][64]
{
    const long i  = (long)blockIdx.x * 256 + threadIdx.x;  // 0..T*64-1
    const long t  = i >> 6;
    const int  r4 = (int)(i & 63);

    const float4* xr = (const float4*)(x + t * HIDDEN) + r4;
    float4 e = xr[0];
    float4 o = xr[64];
    #pragma unroll
    for (int gi = 1; gi < G / 2; ++gi) {      // two independent chains (ILP)
        const float4 a = xr[(2 * gi) * 64];
        const float4 b = xr[(2 * gi + 1) * 64];
        e.x += a.x; e.y += a.y; e.z += a.z; e.w += a.w;
        o.x += b.x; o.y += b.y; o.z += b.z; o.w += b.w;
    }
    e.x += o.x; e.y += o.y; e.z += o.z; e.w += o.w;
    comp_pk[t * 64 + r4] = make_uint2(pkf16(e.x, e.y), pkf16(e.z, e.w));
}

// ---------------------------------------------------------------------------
// k2: write-stream phase, column-split. Wave = 4 tokens x 128 columns:
//     M footprint 64 KB/wave (512 MB total L2 traffic), 8192 waves for full
//     TLP (32 waves/CU). dot2 accumulate, NT coalesced splat stores.
// ---------------------------------------------------------------------------
__global__ __launch_bounds__(256)
void mora_expand(const uint2* __restrict__ comp_pk,     // [T][64]
                 const unsigned int* __restrict__ Mp,   // [128][256] f16 pairs
                 float* __restrict__ out)               // [T, HIDDEN]
{
    __shared__ float ost[4][128];           // per-wave private, no barriers

    const int  tid   = threadIdx.x;
    const int  w     = tid >> 6;
    const int  l     = tid & 63;
    const int  wid   = blockIdx.x * 4 + w;  // 0..8191
    const int  ch    = wid & 1;             // column half 0/1
    const long tok0  = (long)(wid >> 1) * TWX;
    const int  kbase = (ch << 7) + 2 * l;   // this lane's first column

    // comp pairs: lane l holds pair 2l (rows 4l,4l+1) and 2l+1 (rows 4l+2,4l+3)
    unsigned int cp0[TWX], cp1[TWX];
    #pragma unroll
    for (int t = 0; t < TWX; ++t) {
        const uint2 c = comp_pk[(tok0 + t) * 64 + l];   // coalesced 512 B/wave
        cp0[t] = c.x;
        cp1[t] = c.y;
    }

    float acc[TWX][2];
    #pragma unroll
    for (int t = 0; t < TWX; ++t) { acc[t][0] = 0.f; acc[t][1] = 0.f; }

    // pair-rows 4i..4i+3 per iter; lane reads its 2 columns (uint2, 512 B/wave)
    #pragma unroll 4
    for (int i = 0; i < 32; ++i) {
        const uint2 m0 = *(const uint2*)(Mp + (4 * i + 0) * 256 + kbase);
        const uint2 m1 = *(const uint2*)(Mp + (4 * i + 1) * 256 + kbase);
        const uint2 m2 = *(const uint2*)(Mp + (4 * i + 2) * 256 + kbase);
        const uint2 m3 = *(const uint2*)(Mp + (4 * i + 3) * 256 + kbase);
        #pragma unroll
        for (int t = 0; t < TWX; ++t) {
            // pair p lives in lane p>>1, component p&1
            const unsigned s0 = (unsigned)__builtin_amdgcn_readlane((int)cp0[t], 2 * i);
            const unsigned s1 = (unsigned)__builtin_amdgcn_readlane((int)cp1[t], 2 * i);
            const unsigned s2 = (unsigned)__builtin_amdgcn_readlane((int)cp0[t], 2 * i + 1);
            const unsigned s3 = (unsigned)__builtin_amdgcn_readlane((int)cp1[t], 2 * i + 1);
            acc[t][0] = dot2(s0, m0.x, acc[t][0]);
            acc[t][1] = dot2(s0, m0.y, acc[t][1]);
            acc[t][0] = dot2(s1, m1.x, acc[t][0]);
            acc[t][1] = dot2(s1, m1.y, acc[t][1]);
            acc[t][0] = dot2(s2, m2.x, acc[t][0]);
            acc[t][1] = dot2(s2, m2.y, acc[t][1]);
            acc[t][0] = dot2(s3, m3.x, acc[t][0]);
            acc[t][1] = dot2(s3, m3.y, acc[t][1]);
        }
    }

    // restage per wave, then NT coalesced splat stores (8 KiB contiguous/token)
    #pragma unroll
    for (int t = 0; t < TWX; ++t) {
        ((float2*)ost[w])[l] = make_float2(acc[t][0], acc[t][1]);
        f4v* orow = (f4v*)(out + (tok0 + t) * HIDDEN) + (ch << 9);
        #pragma unroll
        for (int s = 0; s < 8; ++s) {
            const float v = ost[w][(s << 4) + (l >> 2)];  // 4-lane bcast, no conflict
            const f4v sp = {v, v, v, v};
            __builtin_nontemporal_store(sp, orow + (s << 6) + l);
        }
    }
}

extern "C" void kernel_launch(void* const* d_in, const int* in_sizes, int n_in,
                              void* d_out, int out_size, void* d_ws, size_t ws_size,
                              hipStream_t stream) {
    const float* x = (const float*)d_in[0];
    const float* M = (const float*)d_in[1];
    float* out     = (float*)d_out;

    unsigned int* Mp      = (unsigned int*)d_ws;               // 128 KiB
    uint2*        comp_pk = (uint2*)((char*)d_ws + 131072);    // 8 MiB

    const int T = in_sizes[0] / HIDDEN;     // 16384 tokens

    hipLaunchKernelGGL(mora_pack, dim3(128), dim3(256), 0, stream, M, Mp);
    hipLaunchKernelGGL(mora_compress, dim3(T * 64 / 256), dim3(256),
                       0, stream, x, comp_pk);
    hipLaunchKernelGGL(mora_expand, dim3(T / TWX * 2 / 4), dim3(256), 0, stream,
                       comp_pk, Mp, out);
}